// Round 13
// baseline (152.431 us; speedup 1.0000x reference)
//
#include <hip/hip_runtime.h>

// VQ-VAE vector quantize + losses, MI355X.
// T=8192 rows, N_E=16384 codes, D=32.
// R28: R27 verified Z-from-candidates (145.6us). rocprof shows the 44.5us
//      256MiB harness ws-fill inside the timed graph (fixed floor); our
//      controllable time ~100us, pass1 ~42 dominant. This round:
//      - e-side bf16-ONLY (drop ehl lo-word): per tile 2 ds_read -> 1,
//        6 MFMA -> 4 (z keeps hi/lo), staging bytes halve (PHT=16, 4
//        barriers/sweep). fb err std ~0.06 log2 (CS worst 1.13).
//      - k_fin threshold exact-refine replaces top-2 re-rank: exact fp32
//        fb for EVERY candidate with key > k1 - 2.5 (margin > 2x worst
//        err + packing); 64-bit LDS atomicMax on {ordered_fb, 16383-idx}
//        gives exact argmin with reference tie-breaking. Deletes the
//        top-2/index merge machinery from scan+reduce.
//      - pass1 m2-based tile-skip (exactly sound with 0.0625 margin):
//        skip the 24 key-update VALU when no acc can beat any m2.
//      Tripwires: absmax > 2.5e-4 -> e-precision/refine failed (revert
//      to hi/lo ehl); pass1 VGPR > 64 = spill; WRITE ~16.9MB expected.

#define N_E 16384
#define ED 32
#define T 8192
#define NS1 16      // pass-1 code splits (1024 codes each)
#define SKIPM -36.0f
#define SKP1M 0.0625f
#define PHT 16      // tiles per staged phase (16KB, bf16-only)

#define K2 288.53900817779268f      // 200 * log2(e)
#define NS2F -144.26950408889634f   // -100 * log2(e)
#define BIAS1 -208.53900817779268f  // 80 + 2*NS2F
#define LN2 0.6931471805599453f

typedef __attribute__((ext_vector_type(8))) short s16x8;
typedef __attribute__((ext_vector_type(4))) float f32x4;

__device__ __forceinline__ float fexp2(float x) { return __builtin_amdgcn_exp2f(x); }
__device__ __forceinline__ float flog2(float x) { return __builtin_amdgcn_logf(x); }
__device__ __forceinline__ float fmed3(float a, float b, float c) {
  return __builtin_amdgcn_fmed3f(a, b, c);
}

// mid-band corrected fb from a packed key (id bits replaced by 512)
__device__ __forceinline__ float midband(float key) {
  return __uint_as_float((__float_as_uint(key) & 0xFFFFFC00u) | 512u);
}

// async global->LDS, 16B per lane; LDS dest = wave-uniform base + lane*16.
__device__ __forceinline__ void gload16(const void* g, void* l) {
  __builtin_amdgcn_global_load_lds(
      (const __attribute__((address_space(1))) void*)g,
      (__attribute__((address_space(3))) void*)l, 16, 0, 0);
}

__device__ __forceinline__ unsigned short f2bf(float x) {
  unsigned u = __float_as_uint(x);
  unsigned r = (u + 0x7FFFu + ((u >> 16) & 1u)) >> 16;
  return (unsigned short)r;
}
__device__ __forceinline__ float bf2f(unsigned short h) {
  return __uint_as_float(((unsigned)h) << 16);
}

// split 8 floats (scaled by sc) of row `row`, group g into hi/lo bf16 frags,
// stored TILE-MAJOR: dst[tile*128 + g*16 + c] (hi), +64 (lo); s16x8 units.
__device__ __forceinline__ void split_store_t(short* __restrict__ base,
    int row, int g, float4 va, float4 vb, float sc) {
  float f[8] = { va.x * sc, va.y * sc, va.z * sc, va.w * sc,
                 vb.x * sc, vb.y * sc, vb.z * sc, vb.w * sc };
  s16x8 H, L;
#pragma unroll
  for (int e = 0; e < 8; ++e) {
    unsigned short h = f2bf(f[e]);
    H[e] = (short)h;
    L[e] = (short)f2bf(f[e] - bf2f(h));
  }
  s16x8* p = (s16x8*)base;
  const int tile = row >> 4, c = row & 15;
  p[tile * 128 + g * 16 + c] = H;
  p[tile * 128 + 64 + g * 16 + c] = L;
}

// bf16-only store, TILE-MAJOR with stride 64: dst[tile*64 + g*16 + c].
__device__ __forceinline__ void split_store_h(short* __restrict__ base,
    int row, int g, float4 va, float4 vb) {
  float f[8] = { va.x, va.y, va.z, va.w, vb.x, vb.y, vb.z, vb.w };
  s16x8 H;
#pragma unroll
  for (int e = 0; e < 8; ++e) H[e] = (short)f2bf(f[e]);
  ((s16x8*)base)[(row >> 4) * 64 + g * 16 + (row & 15)] = H;
}

// --- prep: blocks 0..63 emb rows; 64..95 z transpose; 96..160 zero avg/scal ---
__global__ __launch_bounds__(256) void k_prep(const float* __restrict__ emb,
    const float* __restrict__ z, float* __restrict__ embn,
    float* __restrict__ ses2, float* __restrict__ zf, float* __restrict__ a02,
    short* __restrict__ ehl, short* __restrict__ zhl, float* __restrict__ avg,
    float* __restrict__ scal) {
  if (blockIdx.x < 64) {
    int n = blockIdx.x * 256 + threadIdx.x;
    const float4* r4 = (const float4*)(emb + (size_t)n * ED);
    float4 v[8]; float s = 0.f;
#pragma unroll
    for (int j = 0; j < 8; ++j) {
      v[j] = r4[j];
      s = fmaf(v[j].x, v[j].x, s); s = fmaf(v[j].y, v[j].y, s);
      s = fmaf(v[j].z, v[j].z, s); s = fmaf(v[j].w, v[j].w, s);
    }
    float inv = 1.0f / fmaxf(sqrtf(s), 1e-12f);
    float s2 = 0.f;
    float4* o4 = (float4*)(embn + (size_t)n * ED);
#pragma unroll
    for (int j = 0; j < 8; ++j) {
      float4 w; w.x = v[j].x * inv; w.y = v[j].y * inv;
      w.z = v[j].z * inv; w.w = v[j].w * inv;
      o4[j] = w; v[j] = w;
      s2 = fmaf(w.x, w.x, s2); s2 = fmaf(w.y, w.y, s2);
      s2 = fmaf(w.z, w.z, s2); s2 = fmaf(w.w, w.w, s2);
    }
    ses2[n] = NS2F * s2;               // true value, for the exact refine
#pragma unroll
    for (int g = 0; g < 4; ++g)
      split_store_h(ehl, n, g, v[2 * g], v[2 * g + 1]);
  } else if (blockIdx.x < 96) {
    int t = (blockIdx.x - 64) * 256 + threadIdx.x;
    int b = t >> 8, hw = t & 255;
    const float* base = z + (size_t)b * (ED * 256) + hw;
    float4 v[8]; float s = 0.f;
#pragma unroll
    for (int j = 0; j < 8; ++j) {
      float4 w;
      w.x = base[(4 * j + 0) * 256]; w.y = base[(4 * j + 1) * 256];
      w.z = base[(4 * j + 2) * 256]; w.w = base[(4 * j + 3) * 256];
      v[j] = w;
      s = fmaf(w.x, w.x, s); s = fmaf(w.y, w.y, s);
      s = fmaf(w.z, w.z, s); s = fmaf(w.w, w.w, s);
    }
    float inv = 1.0f / fmaxf(sqrtf(s), 1e-12f);
    float s2 = 0.f;
    float4* o4 = (float4*)(zf + (size_t)t * ED);
#pragma unroll
    for (int j = 0; j < 8; ++j) {
      float4 w; w.x = v[j].x * inv; w.y = v[j].y * inv;
      w.z = v[j].z * inv; w.w = v[j].w * inv;
      o4[j] = w; v[j] = w;
      s2 = fmaf(w.x, w.x, s2); s2 = fmaf(w.y, w.y, s2);
      s2 = fmaf(w.z, w.z, s2); s2 = fmaf(w.w, w.w, s2);
    }
    a02[t] = NS2F * s2;               // only k_fin (exact refine) uses this
#pragma unroll
    for (int g = 0; g < 4; ++g)
      split_store_t(zhl, t, g, v[2 * g], v[2 * g + 1], K2);
  } else if (blockIdx.x < 160) {
    avg[(blockIdx.x - 96) * 256 + threadIdx.x] = 0.f;
  } else {
    if (threadIdx.x < 4) scal[threadIdx.x] = 0.f;  // [0]=sampE [1]=vq
  }
}

// --- pass 1: block = 128 rows (4 waves x 32 = 2 A-pairs), sweeps a
//     1024-code split (64 tiles, 4 phases x 16). B = bf16-ONLY (1KB/tile)
//     staged via gload_lds into 2x16KB dbuf. Per tile: 1 ds_read + 4 MFMA
//     (z hi/lo x e hi). m2-based tile-skip (sound, 0.0625 margin).
//     Packed keys (tile<<4)|c; epilogue = 2 float4 stores. ---
__global__ __launch_bounds__(256, 4) void k_pass1(
    const short* __restrict__ ehl, const short* __restrict__ zhl,
    float* __restrict__ cand1, float* __restrict__ cand2) {
  const int tid = threadIdx.x;
  const int lane = tid & 63, wv = tid >> 6;
  const int q = lane >> 4, c = lane & 15;
  const int rowbase = blockIdx.x * 128 + wv * 32;
  const int NT = (N_E / NS1) / 16;  // 64
  const int NP = NT / PHT;          // 4

  __shared__ s16x8 dbuf[2][PHT * 64];   // 2 x 16KB

  const s16x8* zg = (const s16x8*)zhl;
  const int atile = rowbase >> 4;
  s16x8 ah[2], al[2];
#pragma unroll
  for (int rg = 0; rg < 2; ++rg) {
    ah[rg] = zg[(atile + rg) * 128 + lane];
    al[rg] = zg[(atile + rg) * 128 + 64 + lane];
  }

  f32x4 bias;
#pragma unroll
  for (int r = 0; r < 4; ++r) bias[r] = BIAS1;

  float m1[2][4], m2[2][4];
#pragma unroll
  for (int rg = 0; rg < 2; ++rg)
#pragma unroll
    for (int k = 0; k < 4; ++k) { m1[rg][k] = -1e30f; m2[rg][k] = -1e30f; }
  float m2min = -1e30f;

  const s16x8* eg = (const s16x8*)ehl + (size_t)blockIdx.y * (64 * 64);

  // stage phase 0: 16KB; wave wv covers s16x8 [wv*256, wv*256+256)
#pragma unroll
  for (int j = 0; j < 4; ++j)
    gload16(eg + wv * 256 + j * 64 + lane, &dbuf[0][wv * 256 + j * 64]);
  __syncthreads();

  for (int p = 0; p < NP; ++p) {
    if (p + 1 < NP) {
      const s16x8* gs = eg + (p + 1) * (PHT * 64);
      s16x8* lb = &dbuf[(p + 1) & 1][0];
#pragma unroll
      for (int j = 0; j < 4; ++j)
        gload16(gs + wv * 256 + j * 64 + lane, lb + wv * 256 + j * 64);
    }
    const s16x8* bb = &dbuf[p & 1][0];
#pragma unroll
    for (int tt = 0; tt < PHT; ++tt) {
      s16x8 bh = bb[tt * 64 + lane];
      const unsigned tuc = (((unsigned)(p * PHT + tt)) << 4) | (unsigned)c;

      f32x4 acc0 = __builtin_amdgcn_mfma_f32_16x16x32_bf16(ah[0], bh, bias, 0, 0, 0);
      acc0 = __builtin_amdgcn_mfma_f32_16x16x32_bf16(al[0], bh, acc0, 0, 0, 0);
      f32x4 acc1 = __builtin_amdgcn_mfma_f32_16x16x32_bf16(ah[1], bh, bias, 0, 0, 0);
      acc1 = __builtin_amdgcn_mfma_f32_16x16x32_bf16(al[1], bh, acc1, 0, 0, 0);

      float mx = fmaxf(fmaxf(fmaxf(acc0[0], acc0[1]), fmaxf(acc0[2], acc0[3])),
                       fmaxf(fmaxf(acc1[0], acc1[1]), fmaxf(acc1[2], acc1[3])));
      if (__any(mx > m2min - SKP1M)) {
#pragma unroll
        for (int r = 0; r < 4; ++r) {
          float k0 = __uint_as_float((__float_as_uint(acc0[r]) & 0xFFFFFC00u) | tuc);
          m2[0][r] = fmed3(k0, m1[0][r], m2[0][r]);
          m1[0][r] = fmaxf(m1[0][r], k0);
          float k1v = __uint_as_float((__float_as_uint(acc1[r]) & 0xFFFFFC00u) | tuc);
          m2[1][r] = fmed3(k1v, m1[1][r], m2[1][r]);
          m1[1][r] = fmaxf(m1[1][r], k1v);
        }
        m2min = fminf(fminf(fminf(m2[0][0], m2[0][1]), fminf(m2[0][2], m2[0][3])),
                      fminf(fminf(m2[1][0], m2[1][1]), fminf(m2[1][2], m2[1][3])));
      }
    }
    __syncthreads();
  }

  const int s = blockIdx.y;
#pragma unroll
  for (int rg = 0; rg < 2; ++rg) {
    float4 v1 = make_float4(m1[rg][0], m1[rg][1], m1[rg][2], m1[rg][3]);
    float4 v2 = make_float4(m2[rg][0], m2[rg][1], m2[rg][2], m2[rg][3]);
    const size_t base = (size_t)(s * 16 + c) * T + (rowbase + rg * 16 + q * 4);
    *(float4*)(cand1 + base) = v1;
    *(float4*)(cand2 + base) = v2;
  }
}

// --- fin: 512 blocks x 256 thr = 16 rows x 16 scan-groups, 32 keys/thread
//     in registers. Scan1: k1(max) + Z + S2. Reduce. Scan2: avg atomics
//     (dl > -36) AND threshold exact-refine: for key > k1 - 2.5, exact
//     fp32 fb -> 64-bit LDS atomicMax {ordered_fb, 16383-idx} (exact
//     argmin incl. reference tie-break). g==0: output + vq. ---
__global__ __launch_bounds__(256) void k_fin(
    const float* __restrict__ cand1, const float* __restrict__ cand2,
    const float* __restrict__ zf, const float* __restrict__ embn,
    const float* __restrict__ ses2, const float* __restrict__ a02,
    float* __restrict__ avg, float* __restrict__ scal,
    float* __restrict__ out) {
  const int tid = threadIdx.x;
  const int rr = tid & 15;          // row within block
  const int g  = tid >> 4;          // scan group 0..15
  const int row = blockIdx.x * 16 + rr;

  __shared__ float sZ[256], sS2[256], sk1[256];
  __shared__ unsigned long long rbest[16];
  __shared__ float slZ[16], sth[16], rsE[16], rvq[16];
  if (tid < 16) rbest[tid] = 0ull;

  float ka[16], kb[16];
  float k1 = -1e30f, Z = 0.f, S2 = 0.f;
#pragma unroll
  for (int k = 0; k < 16; ++k) {
    const int u = g * 16 + k;
    const float ca = cand1[(size_t)u * T + row];
    const float cb = cand2[(size_t)u * T + row];
    ka[k] = ca; kb[k] = cb;
    k1 = fmaxf(k1, ca);               // m1 >= m2, so cand1 suffices
    const float fa = midband(ca), fb = midband(cb);
    const float ea = fexp2(fa), eb = fexp2(fb);
    Z += ea + eb;
    S2 = fmaf(ea, fa, fmaf(eb, fb, S2));
  }
  sZ[tid] = Z; sS2[tid] = S2; sk1[tid] = k1;
  __syncthreads();
  for (int st = 8; st >= 1; st >>= 1) {
    if (g < st) {
      const int o = tid + st * 16;
      sZ[tid] += sZ[o]; sS2[tid] += sS2[o];
      sk1[tid] = fmaxf(sk1[tid], sk1[o]);
    }
    __syncthreads();
  }
  if (g == 0) { slZ[rr] = flog2(sZ[rr]); sth[rr] = sk1[rr] - 2.5f; }
  __syncthreads();
  const float lZ = slZ[rr], thr = sth[rr];
  const float a02t = a02[row];

#pragma unroll
  for (int k = 0; k < 16; ++k) {
    const int u = g * 16 + k;
#pragma unroll
    for (int h = 0; h < 2; ++h) {
      const float key = h ? kb[k] : ka[k];
      const unsigned kid = __float_as_uint(key) & 1023u;
      const int idx = (u >> 4) * 1024 + (int)((kid >> 4) << 4) + (int)(kid & 15u);
      const float dl = midband(key) - lZ;
      if (dl > SKIPM) atomicAdd(&avg[idx], fexp2(dl));
      if (key > thr) {
        const float4* er = (const float4*)(embn + (size_t)idx * ED);
        const float4* zr = (const float4*)(zf + (size_t)row * ED);
        float d = 0.f;
#pragma unroll
        for (int j = 0; j < 8; ++j) {
          float4 a = er[j], b = zr[j];
          d = fmaf(a.x, b.x, d); d = fmaf(a.y, b.y, d);
          d = fmaf(a.z, b.z, d); d = fmaf(a.w, b.w, d);
        }
        const float fbx = fmaf(K2, d, a02t + ses2[idx]);
        const unsigned ub = __float_as_uint(fbx);
        const unsigned ord = ub ^ (unsigned)(((int)ub >> 31) | 0x80000000);
        const unsigned long long pk =
            ((unsigned long long)ord << 14) | (unsigned long long)(16383 - idx);
        atomicMax(&rbest[rr], pk);
      }
    }
  }
  __syncthreads();

  if (g == 0) {
    rsE[rr] = sS2[rr] / sZ[rr] - lZ;   // row entropy term = sum p*dl
    const int bi = 16383 - (int)(rbest[rr] & 16383ull);

    const float4* zr4 = (const float4*)(zf + (size_t)row * ED);
    float4 z0 = zr4[0], z1 = zr4[1], z2 = zr4[2], z3 = zr4[3];
    float4 z4 = zr4[4], z5 = zr4[5], z6 = zr4[6], z7 = zr4[7];

    const int b = row >> 8, hw = row & 255;
    float* ob = out + (size_t)b * (ED * 256) + hw;
    float ss = 0.f;
    const float4* e4 = (const float4*)(embn + (size_t)bi * ED);
#pragma unroll
    for (int j = 0; j < 8; ++j) {
      float4 qv = e4[j];
      float4 zv = (j == 0) ? z0 : (j == 1) ? z1 : (j == 2) ? z2 : (j == 3) ? z3
                : (j == 4) ? z4 : (j == 5) ? z5 : (j == 6) ? z6 : z7;
      float df;
      df = qv.x - zv.x; ss = fmaf(df, df, ss); ob[(4 * j + 0) * 256] = zv.x + (qv.x - zv.x);
      df = qv.y - zv.y; ss = fmaf(df, df, ss); ob[(4 * j + 1) * 256] = zv.y + (qv.y - zv.y);
      df = qv.z - zv.z; ss = fmaf(df, df, ss); ob[(4 * j + 2) * 256] = zv.z + (qv.z - zv.z);
      df = qv.w - zv.w; ss = fmaf(df, df, ss); ob[(4 * j + 3) * 256] = zv.w + (qv.w - zv.w);
    }
    rvq[rr] = ss;
  }
  __syncthreads();
  if (tid == 0) {
    float se = 0.f, vq = 0.f;
    for (int i = 0; i < 16; ++i) { se += rsE[i]; vq += rvq[i]; }
    atomicAdd(&scal[0], se);
    atomicAdd(&scal[1], vq);
  }
}

// --- last: 1 block; avg_entropy + final scalars. Stream order after k_fin
//     is the global barrier (no fences/counters). ---
__global__ __launch_bounds__(256) void k_last(const float* __restrict__ avg,
    const float* __restrict__ scal, float* __restrict__ out) {
  const int tid = threadIdx.x;
  __shared__ float red[256];
  float s = 0.f;
  for (int i = tid; i < N_E; i += 256) {
    float a = avg[i] * (1.0f / T);
    s += a * (flog2(a + 1e-5f) * LN2);
  }
  red[tid] = s;
  __syncthreads();
  for (int st = 128; st > 0; st >>= 1) {
    if (tid < st) red[tid] += red[tid + st];
    __syncthreads();
  }
  if (tid == 0) {
    float avg_entropy = -red[0];
    float sample_entropy = -(scal[0] * LN2) * (1.0f / T);
    float vq = scal[1] * (1.0f / (T * ED));
    out[T * ED + 0] = vq;
    out[T * ED + 1] = 0.25f * vq;
    out[T * ED + 2] = 0.1f * (sample_entropy - avg_entropy);
  }
}

extern "C" void kernel_launch(void* const* d_in, const int* in_sizes, int n_in,
                              void* d_out, int out_size, void* d_ws, size_t ws_size,
                              hipStream_t stream) {
  const float* z = (const float*)d_in[0];
  const float* emb = (const float*)d_in[1];
  float* out = (float*)d_out;
  float* w = (float*)d_ws;

  float* embn = w;                          // 524288 f
  float* ses2 = embn + 524288;              // 16384
  float* zf   = ses2 + 16384;               // 262144
  float* a02  = zf + 262144;                // 8192
  short* ehl  = (short*)(a02 + 8192);       // 524288 sh (bf16-only, 1MB)
  short* zhl  = ehl + 524288;               // 524288 sh (hi/lo)
  float* cand1 = (float*)(zhl + 524288);    // 256*T = 2097152 f
  float* cand2 = cand1 + 256 * T;           // 2097152 f
  float* avg  = cand2 + 256 * T;            // 16384
  float* scal = avg + 16384;                // 4: sampE, vq, pad, pad

  k_prep<<<161, 256, 0, stream>>>(emb, z, embn, ses2, zf, a02, ehl, zhl,
                                  avg, scal);
  k_pass1<<<dim3(T / 128, NS1), 256, 0, stream>>>(ehl, zhl, cand1, cand2);
  k_fin<<<T / 16, 256, 0, stream>>>(cand1, cand2, zf, embn, ses2, a02,
                                    avg, scal, out);
  k_last<<<1, 256, 0, stream>>>(avg, scal, out);
}

// Round 14
// 138.434 us; speedup vs baseline: 1.1011x; 1.1011x over previous
//
#include <hip/hip_runtime.h>

// VQ-VAE vector quantize + losses, MI355X.
// T=8192 rows, N_E=16384 codes, D=32.
// R29: R28 post-mortem — e-bf16 + threshold exact-refine VERIFIED (absmax
//      unchanged, FETCH halved) but the m2 tile-skip REGRESSED pass1
//      (46.7us, above the 44.5us ws-fill; R27's was below): ~12 always-
//      paid ops/tile (max-tree + m2min + vote + branch) vs 24 saved at a
//      low skip rate. R29 = R28 minus the skip, nothing else changed:
//      bf16-only e (1 ds_read + 4 MFMA/tile, PHT=16, 4 barriers/sweep),
//      packed 10-bit keys, 2-store epilogue, k_fin threshold exact-refine.
//      Predicted: pass1 ~38-42us, total ~142-147 (new best). If pass1
//      stays ~46 without the skip, structure is at its latency floor ->
//      declare practical roofline (fill 44.5us is harness-fixed).

#define N_E 16384
#define ED 32
#define T 8192
#define NS1 16      // pass-1 code splits (1024 codes each)
#define SKIPM -36.0f
#define PHT 16      // tiles per staged phase (16KB, bf16-only)

#define K2 288.53900817779268f      // 200 * log2(e)
#define NS2F -144.26950408889634f   // -100 * log2(e)
#define BIAS1 -208.53900817779268f  // 80 + 2*NS2F
#define LN2 0.6931471805599453f

typedef __attribute__((ext_vector_type(8))) short s16x8;
typedef __attribute__((ext_vector_type(4))) float f32x4;

__device__ __forceinline__ float fexp2(float x) { return __builtin_amdgcn_exp2f(x); }
__device__ __forceinline__ float flog2(float x) { return __builtin_amdgcn_logf(x); }
__device__ __forceinline__ float fmed3(float a, float b, float c) {
  return __builtin_amdgcn_fmed3f(a, b, c);
}

// mid-band corrected fb from a packed key (id bits replaced by 512)
__device__ __forceinline__ float midband(float key) {
  return __uint_as_float((__float_as_uint(key) & 0xFFFFFC00u) | 512u);
}

// async global->LDS, 16B per lane; LDS dest = wave-uniform base + lane*16.
__device__ __forceinline__ void gload16(const void* g, void* l) {
  __builtin_amdgcn_global_load_lds(
      (const __attribute__((address_space(1))) void*)g,
      (__attribute__((address_space(3))) void*)l, 16, 0, 0);
}

__device__ __forceinline__ unsigned short f2bf(float x) {
  unsigned u = __float_as_uint(x);
  unsigned r = (u + 0x7FFFu + ((u >> 16) & 1u)) >> 16;
  return (unsigned short)r;
}
__device__ __forceinline__ float bf2f(unsigned short h) {
  return __uint_as_float(((unsigned)h) << 16);
}

// split 8 floats (scaled by sc) of row `row`, group g into hi/lo bf16 frags,
// stored TILE-MAJOR: dst[tile*128 + g*16 + c] (hi), +64 (lo); s16x8 units.
__device__ __forceinline__ void split_store_t(short* __restrict__ base,
    int row, int g, float4 va, float4 vb, float sc) {
  float f[8] = { va.x * sc, va.y * sc, va.z * sc, va.w * sc,
                 vb.x * sc, vb.y * sc, vb.z * sc, vb.w * sc };
  s16x8 H, L;
#pragma unroll
  for (int e = 0; e < 8; ++e) {
    unsigned short h = f2bf(f[e]);
    H[e] = (short)h;
    L[e] = (short)f2bf(f[e] - bf2f(h));
  }
  s16x8* p = (s16x8*)base;
  const int tile = row >> 4, c = row & 15;
  p[tile * 128 + g * 16 + c] = H;
  p[tile * 128 + 64 + g * 16 + c] = L;
}

// bf16-only store, TILE-MAJOR with stride 64: dst[tile*64 + g*16 + c].
__device__ __forceinline__ void split_store_h(short* __restrict__ base,
    int row, int g, float4 va, float4 vb) {
  float f[8] = { va.x, va.y, va.z, va.w, vb.x, vb.y, vb.z, vb.w };
  s16x8 H;
#pragma unroll
  for (int e = 0; e < 8; ++e) H[e] = (short)f2bf(f[e]);
  ((s16x8*)base)[(row >> 4) * 64 + g * 16 + (row & 15)] = H;
}

// --- prep: blocks 0..63 emb rows; 64..95 z transpose; 96..160 zero avg/scal ---
__global__ __launch_bounds__(256) void k_prep(const float* __restrict__ emb,
    const float* __restrict__ z, float* __restrict__ embn,
    float* __restrict__ ses2, float* __restrict__ zf, float* __restrict__ a02,
    short* __restrict__ ehl, short* __restrict__ zhl, float* __restrict__ avg,
    float* __restrict__ scal) {
  if (blockIdx.x < 64) {
    int n = blockIdx.x * 256 + threadIdx.x;
    const float4* r4 = (const float4*)(emb + (size_t)n * ED);
    float4 v[8]; float s = 0.f;
#pragma unroll
    for (int j = 0; j < 8; ++j) {
      v[j] = r4[j];
      s = fmaf(v[j].x, v[j].x, s); s = fmaf(v[j].y, v[j].y, s);
      s = fmaf(v[j].z, v[j].z, s); s = fmaf(v[j].w, v[j].w, s);
    }
    float inv = 1.0f / fmaxf(sqrtf(s), 1e-12f);
    float s2 = 0.f;
    float4* o4 = (float4*)(embn + (size_t)n * ED);
#pragma unroll
    for (int j = 0; j < 8; ++j) {
      float4 w; w.x = v[j].x * inv; w.y = v[j].y * inv;
      w.z = v[j].z * inv; w.w = v[j].w * inv;
      o4[j] = w; v[j] = w;
      s2 = fmaf(w.x, w.x, s2); s2 = fmaf(w.y, w.y, s2);
      s2 = fmaf(w.z, w.z, s2); s2 = fmaf(w.w, w.w, s2);
    }
    ses2[n] = NS2F * s2;               // true value, for the exact refine
#pragma unroll
    for (int g = 0; g < 4; ++g)
      split_store_h(ehl, n, g, v[2 * g], v[2 * g + 1]);
  } else if (blockIdx.x < 96) {
    int t = (blockIdx.x - 64) * 256 + threadIdx.x;
    int b = t >> 8, hw = t & 255;
    const float* base = z + (size_t)b * (ED * 256) + hw;
    float4 v[8]; float s = 0.f;
#pragma unroll
    for (int j = 0; j < 8; ++j) {
      float4 w;
      w.x = base[(4 * j + 0) * 256]; w.y = base[(4 * j + 1) * 256];
      w.z = base[(4 * j + 2) * 256]; w.w = base[(4 * j + 3) * 256];
      v[j] = w;
      s = fmaf(w.x, w.x, s); s = fmaf(w.y, w.y, s);
      s = fmaf(w.z, w.z, s); s = fmaf(w.w, w.w, s);
    }
    float inv = 1.0f / fmaxf(sqrtf(s), 1e-12f);
    float s2 = 0.f;
    float4* o4 = (float4*)(zf + (size_t)t * ED);
#pragma unroll
    for (int j = 0; j < 8; ++j) {
      float4 w; w.x = v[j].x * inv; w.y = v[j].y * inv;
      w.z = v[j].z * inv; w.w = v[j].w * inv;
      o4[j] = w; v[j] = w;
      s2 = fmaf(w.x, w.x, s2); s2 = fmaf(w.y, w.y, s2);
      s2 = fmaf(w.z, w.z, s2); s2 = fmaf(w.w, w.w, s2);
    }
    a02[t] = NS2F * s2;               // only k_fin (exact refine) uses this
#pragma unroll
    for (int g = 0; g < 4; ++g)
      split_store_t(zhl, t, g, v[2 * g], v[2 * g + 1], K2);
  } else if (blockIdx.x < 160) {
    avg[(blockIdx.x - 96) * 256 + threadIdx.x] = 0.f;
  } else {
    if (threadIdx.x < 4) scal[threadIdx.x] = 0.f;  // [0]=sampE [1]=vq
  }
}

// --- pass 1: block = 128 rows (4 waves x 32 = 2 A-pairs), sweeps a
//     1024-code split (64 tiles, 4 phases x 16). B = bf16-ONLY (1KB/tile)
//     staged via gload_lds into 2x16KB dbuf. Per tile: 1 ds_read + 4 MFMA
//     (z hi/lo x e hi) + 8x{and_or, med3, max} key updates. No tile-skip
//     (R28 lesson: skip overhead > savings). Epilogue = 2 float4 stores. ---
__global__ __launch_bounds__(256, 4) void k_pass1(
    const short* __restrict__ ehl, const short* __restrict__ zhl,
    float* __restrict__ cand1, float* __restrict__ cand2) {
  const int tid = threadIdx.x;
  const int lane = tid & 63, wv = tid >> 6;
  const int q = lane >> 4, c = lane & 15;
  const int rowbase = blockIdx.x * 128 + wv * 32;
  const int NT = (N_E / NS1) / 16;  // 64
  const int NP = NT / PHT;          // 4

  __shared__ s16x8 dbuf[2][PHT * 64];   // 2 x 16KB

  const s16x8* zg = (const s16x8*)zhl;
  const int atile = rowbase >> 4;
  s16x8 ah[2], al[2];
#pragma unroll
  for (int rg = 0; rg < 2; ++rg) {
    ah[rg] = zg[(atile + rg) * 128 + lane];
    al[rg] = zg[(atile + rg) * 128 + 64 + lane];
  }

  f32x4 bias;
#pragma unroll
  for (int r = 0; r < 4; ++r) bias[r] = BIAS1;

  float m1[2][4], m2[2][4];
#pragma unroll
  for (int rg = 0; rg < 2; ++rg)
#pragma unroll
    for (int k = 0; k < 4; ++k) { m1[rg][k] = -1e30f; m2[rg][k] = -1e30f; }

  const s16x8* eg = (const s16x8*)ehl + (size_t)blockIdx.y * (64 * 64);

  // stage phase 0: 16KB; wave wv covers s16x8 [wv*256, wv*256+256)
#pragma unroll
  for (int j = 0; j < 4; ++j)
    gload16(eg + wv * 256 + j * 64 + lane, &dbuf[0][wv * 256 + j * 64]);
  __syncthreads();

  for (int p = 0; p < NP; ++p) {
    if (p + 1 < NP) {
      const s16x8* gs = eg + (p + 1) * (PHT * 64);
      s16x8* lb = &dbuf[(p + 1) & 1][0];
#pragma unroll
      for (int j = 0; j < 4; ++j)
        gload16(gs + wv * 256 + j * 64 + lane, lb + wv * 256 + j * 64);
    }
    const s16x8* bb = &dbuf[p & 1][0];
#pragma unroll
    for (int tt = 0; tt < PHT; ++tt) {
      s16x8 bh = bb[tt * 64 + lane];
      const unsigned tuc = (((unsigned)(p * PHT + tt)) << 4) | (unsigned)c;

      f32x4 acc0 = __builtin_amdgcn_mfma_f32_16x16x32_bf16(ah[0], bh, bias, 0, 0, 0);
      acc0 = __builtin_amdgcn_mfma_f32_16x16x32_bf16(al[0], bh, acc0, 0, 0, 0);
      f32x4 acc1 = __builtin_amdgcn_mfma_f32_16x16x32_bf16(ah[1], bh, bias, 0, 0, 0);
      acc1 = __builtin_amdgcn_mfma_f32_16x16x32_bf16(al[1], bh, acc1, 0, 0, 0);

#pragma unroll
      for (int r = 0; r < 4; ++r) {
        float k0 = __uint_as_float((__float_as_uint(acc0[r]) & 0xFFFFFC00u) | tuc);
        m2[0][r] = fmed3(k0, m1[0][r], m2[0][r]);
        m1[0][r] = fmaxf(m1[0][r], k0);
        float k1v = __uint_as_float((__float_as_uint(acc1[r]) & 0xFFFFFC00u) | tuc);
        m2[1][r] = fmed3(k1v, m1[1][r], m2[1][r]);
        m1[1][r] = fmaxf(m1[1][r], k1v);
      }
    }
    __syncthreads();
  }

  const int s = blockIdx.y;
#pragma unroll
  for (int rg = 0; rg < 2; ++rg) {
    float4 v1 = make_float4(m1[rg][0], m1[rg][1], m1[rg][2], m1[rg][3]);
    float4 v2 = make_float4(m2[rg][0], m2[rg][1], m2[rg][2], m2[rg][3]);
    const size_t base = (size_t)(s * 16 + c) * T + (rowbase + rg * 16 + q * 4);
    *(float4*)(cand1 + base) = v1;
    *(float4*)(cand2 + base) = v2;
  }
}

// --- fin: 512 blocks x 256 thr = 16 rows x 16 scan-groups, 32 keys/thread
//     in registers. Scan1: k1(max) + Z + S2. Reduce. Scan2: avg atomics
//     (dl > -36) AND threshold exact-refine: for key > k1 - 2.5, exact
//     fp32 fb -> 64-bit LDS atomicMax {ordered_fb, 16383-idx} (exact
//     argmin incl. reference tie-break). g==0: output + vq. ---
__global__ __launch_bounds__(256) void k_fin(
    const float* __restrict__ cand1, const float* __restrict__ cand2,
    const float* __restrict__ zf, const float* __restrict__ embn,
    const float* __restrict__ ses2, const float* __restrict__ a02,
    float* __restrict__ avg, float* __restrict__ scal,
    float* __restrict__ out) {
  const int tid = threadIdx.x;
  const int rr = tid & 15;          // row within block
  const int g  = tid >> 4;          // scan group 0..15
  const int row = blockIdx.x * 16 + rr;

  __shared__ float sZ[256], sS2[256], sk1[256];
  __shared__ unsigned long long rbest[16];
  __shared__ float slZ[16], sth[16], rsE[16], rvq[16];
  if (tid < 16) rbest[tid] = 0ull;

  float ka[16], kb[16];
  float k1 = -1e30f, Z = 0.f, S2 = 0.f;
#pragma unroll
  for (int k = 0; k < 16; ++k) {
    const int u = g * 16 + k;
    const float ca = cand1[(size_t)u * T + row];
    const float cb = cand2[(size_t)u * T + row];
    ka[k] = ca; kb[k] = cb;
    k1 = fmaxf(k1, ca);               // m1 >= m2, so cand1 suffices
    const float fa = midband(ca), fb = midband(cb);
    const float ea = fexp2(fa), eb = fexp2(fb);
    Z += ea + eb;
    S2 = fmaf(ea, fa, fmaf(eb, fb, S2));
  }
  sZ[tid] = Z; sS2[tid] = S2; sk1[tid] = k1;
  __syncthreads();
  for (int st = 8; st >= 1; st >>= 1) {
    if (g < st) {
      const int o = tid + st * 16;
      sZ[tid] += sZ[o]; sS2[tid] += sS2[o];
      sk1[tid] = fmaxf(sk1[tid], sk1[o]);
    }
    __syncthreads();
  }
  if (g == 0) { slZ[rr] = flog2(sZ[rr]); sth[rr] = sk1[rr] - 2.5f; }
  __syncthreads();
  const float lZ = slZ[rr], thr = sth[rr];
  const float a02t = a02[row];

#pragma unroll
  for (int k = 0; k < 16; ++k) {
    const int u = g * 16 + k;
#pragma unroll
    for (int h = 0; h < 2; ++h) {
      const float key = h ? kb[k] : ka[k];
      const unsigned kid = __float_as_uint(key) & 1023u;
      const int idx = (u >> 4) * 1024 + (int)((kid >> 4) << 4) + (int)(kid & 15u);
      const float dl = midband(key) - lZ;
      if (dl > SKIPM) atomicAdd(&avg[idx], fexp2(dl));
      if (key > thr) {
        const float4* er = (const float4*)(embn + (size_t)idx * ED);
        const float4* zr = (const float4*)(zf + (size_t)row * ED);
        float d = 0.f;
#pragma unroll
        for (int j = 0; j < 8; ++j) {
          float4 a = er[j], b = zr[j];
          d = fmaf(a.x, b.x, d); d = fmaf(a.y, b.y, d);
          d = fmaf(a.z, b.z, d); d = fmaf(a.w, b.w, d);
        }
        const float fbx = fmaf(K2, d, a02t + ses2[idx]);
        const unsigned ub = __float_as_uint(fbx);
        const unsigned ord = ub ^ (unsigned)(((int)ub >> 31) | 0x80000000);
        const unsigned long long pk =
            ((unsigned long long)ord << 14) | (unsigned long long)(16383 - idx);
        atomicMax(&rbest[rr], pk);
      }
    }
  }
  __syncthreads();

  if (g == 0) {
    rsE[rr] = sS2[rr] / sZ[rr] - lZ;   // row entropy term = sum p*dl
    const int bi = 16383 - (int)(rbest[rr] & 16383ull);

    const float4* zr4 = (const float4*)(zf + (size_t)row * ED);
    float4 z0 = zr4[0], z1 = zr4[1], z2 = zr4[2], z3 = zr4[3];
    float4 z4 = zr4[4], z5 = zr4[5], z6 = zr4[6], z7 = zr4[7];

    const int b = row >> 8, hw = row & 255;
    float* ob = out + (size_t)b * (ED * 256) + hw;
    float ss = 0.f;
    const float4* e4 = (const float4*)(embn + (size_t)bi * ED);
#pragma unroll
    for (int j = 0; j < 8; ++j) {
      float4 qv = e4[j];
      float4 zv = (j == 0) ? z0 : (j == 1) ? z1 : (j == 2) ? z2 : (j == 3) ? z3
                : (j == 4) ? z4 : (j == 5) ? z5 : (j == 6) ? z6 : z7;
      float df;
      df = qv.x - zv.x; ss = fmaf(df, df, ss); ob[(4 * j + 0) * 256] = zv.x + (qv.x - zv.x);
      df = qv.y - zv.y; ss = fmaf(df, df, ss); ob[(4 * j + 1) * 256] = zv.y + (qv.y - zv.y);
      df = qv.z - zv.z; ss = fmaf(df, df, ss); ob[(4 * j + 2) * 256] = zv.z + (qv.z - zv.z);
      df = qv.w - zv.w; ss = fmaf(df, df, ss); ob[(4 * j + 3) * 256] = zv.w + (qv.w - zv.w);
    }
    rvq[rr] = ss;
  }
  __syncthreads();
  if (tid == 0) {
    float se = 0.f, vq = 0.f;
    for (int i = 0; i < 16; ++i) { se += rsE[i]; vq += rvq[i]; }
    atomicAdd(&scal[0], se);
    atomicAdd(&scal[1], vq);
  }
}

// --- last: 1 block; avg_entropy + final scalars. Stream order after k_fin
//     is the global barrier (no fences/counters). ---
__global__ __launch_bounds__(256) void k_last(const float* __restrict__ avg,
    const float* __restrict__ scal, float* __restrict__ out) {
  const int tid = threadIdx.x;
  __shared__ float red[256];
  float s = 0.f;
  for (int i = tid; i < N_E; i += 256) {
    float a = avg[i] * (1.0f / T);
    s += a * (flog2(a + 1e-5f) * LN2);
  }
  red[tid] = s;
  __syncthreads();
  for (int st = 128; st > 0; st >>= 1) {
    if (tid < st) red[tid] += red[tid + st];
    __syncthreads();
  }
  if (tid == 0) {
    float avg_entropy = -red[0];
    float sample_entropy = -(scal[0] * LN2) * (1.0f / T);
    float vq = scal[1] * (1.0f / (T * ED));
    out[T * ED + 0] = vq;
    out[T * ED + 1] = 0.25f * vq;
    out[T * ED + 2] = 0.1f * (sample_entropy - avg_entropy);
  }
}

extern "C" void kernel_launch(void* const* d_in, const int* in_sizes, int n_in,
                              void* d_out, int out_size, void* d_ws, size_t ws_size,
                              hipStream_t stream) {
  const float* z = (const float*)d_in[0];
  const float* emb = (const float*)d_in[1];
  float* out = (float*)d_out;
  float* w = (float*)d_ws;

  float* embn = w;                          // 524288 f
  float* ses2 = embn + 524288;              // 16384
  float* zf   = ses2 + 16384;               // 262144
  float* a02  = zf + 262144;                // 8192
  short* ehl  = (short*)(a02 + 8192);       // 524288 sh (bf16-only, 1MB)
  short* zhl  = ehl + 524288;               // 524288 sh (hi/lo)
  float* cand1 = (float*)(zhl + 524288);    // 256*T = 2097152 f
  float* cand2 = cand1 + 256 * T;           // 2097152 f
  float* avg  = cand2 + 256 * T;            // 16384
  float* scal = avg + 16384;                // 4: sampE, vq, pad, pad

  k_prep<<<161, 256, 0, stream>>>(emb, z, embn, ses2, zf, a02, ehl, zhl,
                                  avg, scal);
  k_pass1<<<dim3(T / 128, NS1), 256, 0, stream>>>(ehl, zhl, cand1, cand2);
  k_fin<<<T / 16, 256, 0, stream>>>(cand1, cand2, zf, embn, ses2, a02,
                                    avg, scal, out);
  k_last<<<1, 256, 0, stream>>>(avg, scal, out);
}

// Round 15
// 136.199 us; speedup vs baseline: 1.1192x; 1.0164x over previous
//
#include <hip/hip_runtime.h>

// VQ-VAE vector quantize + losses, MI355X.
// T=8192 rows, N_E=16384 codes, D=32.
// R30: R29 = 138.4us best; top dispatches now the harness's 256MiB ws-fill
//      (44.5us, uncontrollable). Controllable ~93us: pass1 ~40, prep ~12,
//      fin ~10. Two instruction-count cuts:
//      - pass1 survey on z-hi x e-hi ONLY (2 MFMA/tile, was 4). Combined
//        two-sided bf16 error E <= 1.13 worst (CS, unit vectors); refine
//        margin widened 2.5 -> 5.0 (> 2E+eps = 2.3, 2x headroom). Same
//        verified error class as R28/R29.
//      - k_fin deferred-exp2: scan A = pure max -> reduce k1 -> scan B
//        exp2/S2 only for key > k1-36 (~0.5/thread; was 32/thread) ->
//        reduce Z -> scan C rare avg atomics + margin-5 exact refine.
//        ~4M exp2 -> ~100K.
//      Tripwires: absmax > 2.5e-4 -> z-hi survey failed (restore z-lo);
//      pass1 VGPR > 64 = spill; WRITE ~16.4MB expected.

#define N_E 16384
#define ED 32
#define T 8192
#define NS1 16      // pass-1 code splits (1024 codes each)
#define ZTH 36.0f   // Z-coverage window below row max
#define RTH 5.0f    // exact-refine margin (> 2*E_worst + quant)
#define PHT 16      // tiles per staged phase (16KB, bf16-only)

#define K2 288.53900817779268f      // 200 * log2(e)
#define NS2F -144.26950408889634f   // -100 * log2(e)
#define BIAS1 -208.53900817779268f  // 80 + 2*NS2F
#define LN2 0.6931471805599453f

typedef __attribute__((ext_vector_type(8))) short s16x8;
typedef __attribute__((ext_vector_type(4))) float f32x4;

__device__ __forceinline__ float fexp2(float x) { return __builtin_amdgcn_exp2f(x); }
__device__ __forceinline__ float flog2(float x) { return __builtin_amdgcn_logf(x); }
__device__ __forceinline__ float fmed3(float a, float b, float c) {
  return __builtin_amdgcn_fmed3f(a, b, c);
}

// mid-band corrected fb from a packed key (id bits replaced by 512)
__device__ __forceinline__ float midband(float key) {
  return __uint_as_float((__float_as_uint(key) & 0xFFFFFC00u) | 512u);
}

// async global->LDS, 16B per lane; LDS dest = wave-uniform base + lane*16.
__device__ __forceinline__ void gload16(const void* g, void* l) {
  __builtin_amdgcn_global_load_lds(
      (const __attribute__((address_space(1))) void*)g,
      (__attribute__((address_space(3))) void*)l, 16, 0, 0);
}

__device__ __forceinline__ unsigned short f2bf(float x) {
  unsigned u = __float_as_uint(x);
  unsigned r = (u + 0x7FFFu + ((u >> 16) & 1u)) >> 16;
  return (unsigned short)r;
}
__device__ __forceinline__ float bf2f(unsigned short h) {
  return __uint_as_float(((unsigned)h) << 16);
}

// split 8 floats (scaled by sc) of row `row`, group g into hi/lo bf16 frags,
// stored TILE-MAJOR: dst[tile*128 + g*16 + c] (hi), +64 (lo); s16x8 units.
__device__ __forceinline__ void split_store_t(short* __restrict__ base,
    int row, int g, float4 va, float4 vb, float sc) {
  float f[8] = { va.x * sc, va.y * sc, va.z * sc, va.w * sc,
                 vb.x * sc, vb.y * sc, vb.z * sc, vb.w * sc };
  s16x8 H, L;
#pragma unroll
  for (int e = 0; e < 8; ++e) {
    unsigned short h = f2bf(f[e]);
    H[e] = (short)h;
    L[e] = (short)f2bf(f[e] - bf2f(h));
  }
  s16x8* p = (s16x8*)base;
  const int tile = row >> 4, c = row & 15;
  p[tile * 128 + g * 16 + c] = H;
  p[tile * 128 + 64 + g * 16 + c] = L;
}

// bf16-only store, TILE-MAJOR with stride 64: dst[tile*64 + g*16 + c].
__device__ __forceinline__ void split_store_h(short* __restrict__ base,
    int row, int g, float4 va, float4 vb) {
  float f[8] = { va.x, va.y, va.z, va.w, vb.x, vb.y, vb.z, vb.w };
  s16x8 H;
#pragma unroll
  for (int e = 0; e < 8; ++e) H[e] = (short)f2bf(f[e]);
  ((s16x8*)base)[(row >> 4) * 64 + g * 16 + (row & 15)] = H;
}

// --- prep: blocks 0..63 emb rows; 64..95 z transpose; 96..160 zero avg/scal ---
__global__ __launch_bounds__(256) void k_prep(const float* __restrict__ emb,
    const float* __restrict__ z, float* __restrict__ embn,
    float* __restrict__ ses2, float* __restrict__ zf, float* __restrict__ a02,
    short* __restrict__ ehl, short* __restrict__ zhl, float* __restrict__ avg,
    float* __restrict__ scal) {
  if (blockIdx.x < 64) {
    int n = blockIdx.x * 256 + threadIdx.x;
    const float4* r4 = (const float4*)(emb + (size_t)n * ED);
    float4 v[8]; float s = 0.f;
#pragma unroll
    for (int j = 0; j < 8; ++j) {
      v[j] = r4[j];
      s = fmaf(v[j].x, v[j].x, s); s = fmaf(v[j].y, v[j].y, s);
      s = fmaf(v[j].z, v[j].z, s); s = fmaf(v[j].w, v[j].w, s);
    }
    float inv = 1.0f / fmaxf(sqrtf(s), 1e-12f);
    float s2 = 0.f;
    float4* o4 = (float4*)(embn + (size_t)n * ED);
#pragma unroll
    for (int j = 0; j < 8; ++j) {
      float4 w; w.x = v[j].x * inv; w.y = v[j].y * inv;
      w.z = v[j].z * inv; w.w = v[j].w * inv;
      o4[j] = w; v[j] = w;
      s2 = fmaf(w.x, w.x, s2); s2 = fmaf(w.y, w.y, s2);
      s2 = fmaf(w.z, w.z, s2); s2 = fmaf(w.w, w.w, s2);
    }
    ses2[n] = NS2F * s2;               // true value, for the exact refine
#pragma unroll
    for (int g = 0; g < 4; ++g)
      split_store_h(ehl, n, g, v[2 * g], v[2 * g + 1]);
  } else if (blockIdx.x < 96) {
    int t = (blockIdx.x - 64) * 256 + threadIdx.x;
    int b = t >> 8, hw = t & 255;
    const float* base = z + (size_t)b * (ED * 256) + hw;
    float4 v[8]; float s = 0.f;
#pragma unroll
    for (int j = 0; j < 8; ++j) {
      float4 w;
      w.x = base[(4 * j + 0) * 256]; w.y = base[(4 * j + 1) * 256];
      w.z = base[(4 * j + 2) * 256]; w.w = base[(4 * j + 3) * 256];
      v[j] = w;
      s = fmaf(w.x, w.x, s); s = fmaf(w.y, w.y, s);
      s = fmaf(w.z, w.z, s); s = fmaf(w.w, w.w, s);
    }
    float inv = 1.0f / fmaxf(sqrtf(s), 1e-12f);
    float s2 = 0.f;
    float4* o4 = (float4*)(zf + (size_t)t * ED);
#pragma unroll
    for (int j = 0; j < 8; ++j) {
      float4 w; w.x = v[j].x * inv; w.y = v[j].y * inv;
      w.z = v[j].z * inv; w.w = v[j].w * inv;
      o4[j] = w; v[j] = w;
      s2 = fmaf(w.x, w.x, s2); s2 = fmaf(w.y, w.y, s2);
      s2 = fmaf(w.z, w.z, s2); s2 = fmaf(w.w, w.w, s2);
    }
    a02[t] = NS2F * s2;               // only k_fin (exact refine) uses this
#pragma unroll
    for (int g = 0; g < 4; ++g)
      split_store_t(zhl, t, g, v[2 * g], v[2 * g + 1], K2);
  } else if (blockIdx.x < 160) {
    avg[(blockIdx.x - 96) * 256 + threadIdx.x] = 0.f;
  } else {
    if (threadIdx.x < 4) scal[threadIdx.x] = 0.f;  // [0]=sampE [1]=vq
  }
}

// --- pass 1: block = 128 rows (4 waves x 32 = 2 A-frags), sweeps a
//     1024-code split (64 tiles, 4 phases x 16). Survey = z-hi x e-hi
//     ONLY: 1 ds_read + 2 MFMA/tile + 8x{and_or, med3, max}. Exactness
//     recovered by k_fin's margin-5 refine. Epilogue = 2 float4 stores. ---
__global__ __launch_bounds__(256, 4) void k_pass1(
    const short* __restrict__ ehl, const short* __restrict__ zhl,
    float* __restrict__ cand1, float* __restrict__ cand2) {
  const int tid = threadIdx.x;
  const int lane = tid & 63, wv = tid >> 6;
  const int q = lane >> 4, c = lane & 15;
  const int rowbase = blockIdx.x * 128 + wv * 32;
  const int NT = (N_E / NS1) / 16;  // 64
  const int NP = NT / PHT;          // 4

  __shared__ s16x8 dbuf[2][PHT * 64];   // 2 x 16KB

  const s16x8* zg = (const s16x8*)zhl;
  const int atile = rowbase >> 4;
  s16x8 ah[2];
#pragma unroll
  for (int rg = 0; rg < 2; ++rg)
    ah[rg] = zg[(atile + rg) * 128 + lane];     // hi words only

  f32x4 bias;
#pragma unroll
  for (int r = 0; r < 4; ++r) bias[r] = BIAS1;

  float m1[2][4], m2[2][4];
#pragma unroll
  for (int rg = 0; rg < 2; ++rg)
#pragma unroll
    for (int k = 0; k < 4; ++k) { m1[rg][k] = -1e30f; m2[rg][k] = -1e30f; }

  const s16x8* eg = (const s16x8*)ehl + (size_t)blockIdx.y * (64 * 64);

  // stage phase 0: 16KB; wave wv covers s16x8 [wv*256, wv*256+256)
#pragma unroll
  for (int j = 0; j < 4; ++j)
    gload16(eg + wv * 256 + j * 64 + lane, &dbuf[0][wv * 256 + j * 64]);
  __syncthreads();

  for (int p = 0; p < NP; ++p) {
    if (p + 1 < NP) {
      const s16x8* gs = eg + (p + 1) * (PHT * 64);
      s16x8* lb = &dbuf[(p + 1) & 1][0];
#pragma unroll
      for (int j = 0; j < 4; ++j)
        gload16(gs + wv * 256 + j * 64 + lane, lb + wv * 256 + j * 64);
    }
    const s16x8* bb = &dbuf[p & 1][0];
#pragma unroll
    for (int tt = 0; tt < PHT; ++tt) {
      s16x8 bh = bb[tt * 64 + lane];
      const unsigned tuc = (((unsigned)(p * PHT + tt)) << 4) | (unsigned)c;

      f32x4 acc0 = __builtin_amdgcn_mfma_f32_16x16x32_bf16(ah[0], bh, bias, 0, 0, 0);
      f32x4 acc1 = __builtin_amdgcn_mfma_f32_16x16x32_bf16(ah[1], bh, bias, 0, 0, 0);

#pragma unroll
      for (int r = 0; r < 4; ++r) {
        float k0 = __uint_as_float((__float_as_uint(acc0[r]) & 0xFFFFFC00u) | tuc);
        m2[0][r] = fmed3(k0, m1[0][r], m2[0][r]);
        m1[0][r] = fmaxf(m1[0][r], k0);
        float k1v = __uint_as_float((__float_as_uint(acc1[r]) & 0xFFFFFC00u) | tuc);
        m2[1][r] = fmed3(k1v, m1[1][r], m2[1][r]);
        m1[1][r] = fmaxf(m1[1][r], k1v);
      }
    }
    __syncthreads();
  }

  const int s = blockIdx.y;
#pragma unroll
  for (int rg = 0; rg < 2; ++rg) {
    float4 v1 = make_float4(m1[rg][0], m1[rg][1], m1[rg][2], m1[rg][3]);
    float4 v2 = make_float4(m2[rg][0], m2[rg][1], m2[rg][2], m2[rg][3]);
    const size_t base = (size_t)(s * 16 + c) * T + (rowbase + rg * 16 + q * 4);
    *(float4*)(cand1 + base) = v1;
    *(float4*)(cand2 + base) = v2;
  }
}

// --- fin: 512 blocks x 256 thr = 16 rows x 16 scan-groups, 32 keys/thread
//     in registers. Scan A: k1 = max. Reduce. Scan B: Z,S2 via exp2 ONLY
//     for key > k1-36 (~0.5/thread). Reduce. Scan C: avg atomics (same
//     window) + margin-5 exact refine -> 64-bit LDS atomicMax
//     {ordered_fb, 16383-idx}. g==0: output + vq. ---
__global__ __launch_bounds__(256) void k_fin(
    const float* __restrict__ cand1, const float* __restrict__ cand2,
    const float* __restrict__ zf, const float* __restrict__ embn,
    const float* __restrict__ ses2, const float* __restrict__ a02,
    float* __restrict__ avg, float* __restrict__ scal,
    float* __restrict__ out) {
  const int tid = threadIdx.x;
  const int rr = tid & 15;          // row within block
  const int g  = tid >> 4;          // scan group 0..15
  const int row = blockIdx.x * 16 + rr;

  __shared__ float sZ[256], sS2[256], sk1[256];
  __shared__ unsigned long long rbest[16];
  __shared__ float slZ[16], rsE[16], rvq[16];
  if (tid < 16) rbest[tid] = 0ull;

  float ka[16], kb[16];
  float k1 = -1e30f;
#pragma unroll
  for (int k = 0; k < 16; ++k) {
    const int u = g * 16 + k;
    ka[k] = cand1[(size_t)u * T + row];
    kb[k] = cand2[(size_t)u * T + row];
    k1 = fmaxf(k1, ka[k]);            // m1 >= m2, so cand1 suffices
  }
  sk1[tid] = k1;
  __syncthreads();
  for (int st = 8; st >= 1; st >>= 1) {
    if (g < st) sk1[tid] = fmaxf(sk1[tid], sk1[tid + st * 16]);
    __syncthreads();
  }
  const float k1r = sk1[rr];
  const float zth = k1r - ZTH, thr = k1r - RTH;

  // scan B: Z, S2 over the significant window only
  float Z = 0.f, S2 = 0.f;
#pragma unroll
  for (int k = 0; k < 16; ++k) {
    if (ka[k] > zth) {
      const float f = midband(ka[k]);
      const float e = fexp2(f);
      Z += e; S2 = fmaf(e, f, S2);
    }
    if (kb[k] > zth) {
      const float f = midband(kb[k]);
      const float e = fexp2(f);
      Z += e; S2 = fmaf(e, f, S2);
    }
  }
  sZ[tid] = Z; sS2[tid] = S2;
  __syncthreads();
  for (int st = 8; st >= 1; st >>= 1) {
    if (g < st) { sZ[tid] += sZ[tid + st * 16]; sS2[tid] += sS2[tid + st * 16]; }
    __syncthreads();
  }
  if (g == 0) slZ[rr] = flog2(sZ[rr]);
  __syncthreads();
  const float lZ = slZ[rr];
  const float a02t = a02[row];

  // scan C: avg atomics + margin-5 exact refine (rare)
#pragma unroll
  for (int k = 0; k < 16; ++k) {
    const int u = g * 16 + k;
#pragma unroll
    for (int h = 0; h < 2; ++h) {
      const float key = h ? kb[k] : ka[k];
      if (key > zth) {
        const unsigned kid = __float_as_uint(key) & 1023u;
        const int idx = (u >> 4) * 1024 + (int)((kid >> 4) << 4) + (int)(kid & 15u);
        atomicAdd(&avg[idx], fexp2(midband(key) - lZ));
        if (key > thr) {
          const float4* er = (const float4*)(embn + (size_t)idx * ED);
          const float4* zr = (const float4*)(zf + (size_t)row * ED);
          float d = 0.f;
#pragma unroll
          for (int j = 0; j < 8; ++j) {
            float4 a = er[j], b = zr[j];
            d = fmaf(a.x, b.x, d); d = fmaf(a.y, b.y, d);
            d = fmaf(a.z, b.z, d); d = fmaf(a.w, b.w, d);
          }
          const float fbx = fmaf(K2, d, a02t + ses2[idx]);
          const unsigned ub = __float_as_uint(fbx);
          const unsigned ord = ub ^ (unsigned)(((int)ub >> 31) | 0x80000000);
          const unsigned long long pk =
              ((unsigned long long)ord << 14) | (unsigned long long)(16383 - idx);
          atomicMax(&rbest[rr], pk);
        }
      }
    }
  }
  __syncthreads();

  if (g == 0) {
    rsE[rr] = sS2[rr] / sZ[rr] - lZ;   // row entropy term = sum p*dl
    const int bi = 16383 - (int)(rbest[rr] & 16383ull);

    const float4* zr4 = (const float4*)(zf + (size_t)row * ED);
    float4 z0 = zr4[0], z1 = zr4[1], z2 = zr4[2], z3 = zr4[3];
    float4 z4 = zr4[4], z5 = zr4[5], z6 = zr4[6], z7 = zr4[7];

    const int b = row >> 8, hw = row & 255;
    float* ob = out + (size_t)b * (ED * 256) + hw;
    float ss = 0.f;
    const float4* e4 = (const float4*)(embn + (size_t)bi * ED);
#pragma unroll
    for (int j = 0; j < 8; ++j) {
      float4 qv = e4[j];
      float4 zv = (j == 0) ? z0 : (j == 1) ? z1 : (j == 2) ? z2 : (j == 3) ? z3
                : (j == 4) ? z4 : (j == 5) ? z5 : (j == 6) ? z6 : z7;
      float df;
      df = qv.x - zv.x; ss = fmaf(df, df, ss); ob[(4 * j + 0) * 256] = zv.x + (qv.x - zv.x);
      df = qv.y - zv.y; ss = fmaf(df, df, ss); ob[(4 * j + 1) * 256] = zv.y + (qv.y - zv.y);
      df = qv.z - zv.z; ss = fmaf(df, df, ss); ob[(4 * j + 2) * 256] = zv.z + (qv.z - zv.z);
      df = qv.w - zv.w; ss = fmaf(df, df, ss); ob[(4 * j + 3) * 256] = zv.w + (qv.w - zv.w);
    }
    rvq[rr] = ss;
  }
  __syncthreads();
  if (tid == 0) {
    float se = 0.f, vq = 0.f;
    for (int i = 0; i < 16; ++i) { se += rsE[i]; vq += rvq[i]; }
    atomicAdd(&scal[0], se);
    atomicAdd(&scal[1], vq);
  }
}

// --- last: 1 block; avg_entropy + final scalars. Stream order after k_fin
//     is the global barrier (no fences/counters). ---
__global__ __launch_bounds__(256) void k_last(const float* __restrict__ avg,
    const float* __restrict__ scal, float* __restrict__ out) {
  const int tid = threadIdx.x;
  __shared__ float red[256];
  float s = 0.f;
  for (int i = tid; i < N_E; i += 256) {
    float a = avg[i] * (1.0f / T);
    s += a * (flog2(a + 1e-5f) * LN2);
  }
  red[tid] = s;
  __syncthreads();
  for (int st = 128; st > 0; st >>= 1) {
    if (tid < st) red[tid] += red[tid + st];
    __syncthreads();
  }
  if (tid == 0) {
    float avg_entropy = -red[0];
    float sample_entropy = -(scal[0] * LN2) * (1.0f / T);
    float vq = scal[1] * (1.0f / (T * ED));
    out[T * ED + 0] = vq;
    out[T * ED + 1] = 0.25f * vq;
    out[T * ED + 2] = 0.1f * (sample_entropy - avg_entropy);
  }
}

extern "C" void kernel_launch(void* const* d_in, const int* in_sizes, int n_in,
                              void* d_out, int out_size, void* d_ws, size_t ws_size,
                              hipStream_t stream) {
  const float* z = (const float*)d_in[0];
  const float* emb = (const float*)d_in[1];
  float* out = (float*)d_out;
  float* w = (float*)d_ws;

  float* embn = w;                          // 524288 f
  float* ses2 = embn + 524288;              // 16384
  float* zf   = ses2 + 16384;               // 262144
  float* a02  = zf + 262144;                // 8192
  short* ehl  = (short*)(a02 + 8192);       // 524288 sh (bf16-only, 1MB)
  short* zhl  = ehl + 524288;               // 524288 sh (hi/lo)
  float* cand1 = (float*)(zhl + 524288);    // 256*T = 2097152 f
  float* cand2 = cand1 + 256 * T;           // 2097152 f
  float* avg  = cand2 + 256 * T;            // 16384
  float* scal = avg + 16384;                // 4: sampE, vq, pad, pad

  k_prep<<<161, 256, 0, stream>>>(emb, z, embn, ses2, zf, a02, ehl, zhl,
                                  avg, scal);
  k_pass1<<<dim3(T / 128, NS1), 256, 0, stream>>>(ehl, zhl, cand1, cand2);
  k_fin<<<T / 16, 256, 0, stream>>>(cand1, cand2, zf, embn, ses2, a02,
                                    avg, scal, out);
  k_last<<<1, 256, 0, stream>>>(avg, scal, out);
}